// Round 10
// baseline (201.982 us; speedup 1.0000x reference)
//
#include <hip/hip_runtime.h>

#define LOG2E 1.4426950408889634f
#define RNB 32   // reverb grid blocks: 4 batches x 8 blocks; per-batch counted barrier

typedef float v2f __attribute__((ext_vector_type(2)));

// fast sigmoid: rcp approx ~1e-6 rel; tolerance headroom is ~250x
__device__ __forceinline__ float fsig(float z) {
    return __builtin_amdgcn_rcpf(1.0f + exp2f(-z * LOG2E));
}

// ---------------------------------------------------------------------------
// VALU polynomial exp2 for a packed pair, args <= 0 (exact row-max ensures).
// deg-5 Taylor of 2^f on [-0.5,0.5]: rel err ~2.4e-6. Scale 2^k via exponent
// bit-construction; clamp at -126 so k+127 >= 1 (k+127==0 would give e=0,
// k+127<0 garbage). Runs on the VALU pipe, offloading the trans pipe.
// ---------------------------------------------------------------------------
__device__ __forceinline__ v2f exp2_poly2(v2f a) {
    a.x = fmaxf(a.x, -126.0f);
    a.y = fmaxf(a.y, -126.0f);
    float rx = __builtin_rintf(a.x), ry = __builtin_rintf(a.y);
    v2f f = (v2f){a.x - rx, a.y - ry};
    v2f p = (v2f){1.3333558e-3f, 1.3333558e-3f};
    p = __builtin_elementwise_fma(p, f, (v2f){9.6181291e-3f, 9.6181291e-3f});
    p = __builtin_elementwise_fma(p, f, (v2f){5.5504109e-2f, 5.5504109e-2f});
    p = __builtin_elementwise_fma(p, f, (v2f){2.4022650e-1f, 2.4022650e-1f});
    p = __builtin_elementwise_fma(p, f, (v2f){6.9314718e-1f, 6.9314718e-1f});
    p = __builtin_elementwise_fma(p, f, (v2f){1.0f, 1.0f});
    float sx = __int_as_float(((int)rx + 127) << 23);
    float sy = __int_as_float(((int)ry + 127) << 23);
    return (v2f){p.x * sx, p.y * sy};
}

// ---------------------------------------------------------------------------
// Device-coherent g-buffer access: relaxed agent-scope atomics -> sc1
// load/store (bypass non-coherent L1/L2, served at the device coherence
// point). Per-access coherence => no wbl2/inv fences anywhere.
// ---------------------------------------------------------------------------
__device__ __forceinline__ float4 ld_fb(const unsigned long long* p) {
    unsigned long long a = __hip_atomic_load(p,     __ATOMIC_RELAXED, __HIP_MEMORY_SCOPE_AGENT);
    unsigned long long b = __hip_atomic_load(p + 1, __ATOMIC_RELAXED, __HIP_MEMORY_SCOPE_AGENT);
    float2 lo = __builtin_bit_cast(float2, a);
    float2 hi = __builtin_bit_cast(float2, b);
    return make_float4(lo.x, lo.y, hi.x, hi.y);
}

__device__ __forceinline__ void st_fb(unsigned long long* p, float4 v) {
    __hip_atomic_store(p,     __builtin_bit_cast(unsigned long long, make_float2(v.x, v.y)),
                       __ATOMIC_RELAXED, __HIP_MEMORY_SCOPE_AGENT);
    __hip_atomic_store(p + 1, __builtin_bit_cast(unsigned long long, make_float2(v.z, v.w)),
                       __ATOMIC_RELAXED, __HIP_MEMORY_SCOPE_AGENT);
}

__global__ __launch_bounds__(256) void bar_init(unsigned* cnt) {
    for (int j = threadIdx.x; j < 1024; j += 256) cnt[j] = 0u;   // 4 batches x 15 slots x 64B
}

// ---------------------------------------------------------------------------
// conv3x3(roll(fb)*fade) + damping MLP at one pixel, fb in LDS (full image
// replicated per block). Weights live in VGPRs (wr), fades in LDS.
// ---------------------------------------------------------------------------
__device__ __forceinline__ void conv_damp_l(
    const float4* __restrict__ src, int yq, int xq, int ys, int xs,
    const float* fe, const float4 wr[9][4],
    const float4 d1w0, const float4 d1w1, const float2 d1b, const float4 d2p[4],
    float rv[4])
{
    float r[4] = { d2p[0].w, d2p[1].w, d2p[2].w, d2p[3].w };   // conv bias (fbb)
    #pragma unroll
    for (int a = 0; a < 3; ++a) {
        int yy = yq - 1 + a;
        float fy = fe[yy + 1];                       // 0 outside image -> zero pad
        const float4* rowp = src + (((yy - ys) & 63) << 6);
        #pragma unroll
        for (int qq = 0; qq < 3; ++qq) {
            int xt = xq - 1 + qq;
            float f = fy * fe[xt + 1];
            float4 v = rowp[(xt - xs) & 63];
            float s0 = v.x * f, s1 = v.y * f, s2 = v.z * f, s3 = v.w * f;
            #pragma unroll
            for (int co = 0; co < 4; ++co) {
                float4 w = wr[a * 3 + qq][co];
                r[co] = fmaf(w.x, s0, fmaf(w.y, s1, fmaf(w.z, s2, fmaf(w.w, s3, r[co]))));
            }
        }
    }
    float z0 = fmaf(d1w0.x, r[0], fmaf(d1w0.y, r[1], fmaf(d1w0.z, r[2], fmaf(d1w0.w, r[3], d1b.x))));
    float z1 = fmaf(d1w1.x, r[0], fmaf(d1w1.y, r[1], fmaf(d1w1.z, r[2], fmaf(d1w1.w, r[3], d1b.y))));
    float h0 = z0 * fsig(z0);
    float h1 = z1 * fsig(z1);
    #pragma unroll
    for (int c = 0; c < 4; ++c) {
        float dm = fsig(fmaf(d2p[c].x, h0, fmaf(d2p[c].y, h1, d2p[c].z)));
        rv[c] = r[c] * dm;
    }
}

// ---------------------------------------------------------------------------
// Kernel 1: multi-block reverb, LDS-replicated state. R3-EXACT (measured
// 48.8us): counted per-batch barrier, tid0 sole adder+poller, block-wide
// release via second syncthreads. R4/R5/R7/R8 lessons: more pollers, fewer
// barriers, and single-CU variants all regress.
// ---------------------------------------------------------------------------
__global__ __launch_bounds__(512) void reverb_mb(
    const float* __restrict__ x, const float* __restrict__ rw, const float* __restrict__ dl,
    const float* __restrict__ fbw, const float* __restrict__ fbb,
    const float* __restrict__ d1wg, const float* __restrict__ d1bg,
    const float* __restrict__ d2wg, const float* __restrict__ d2bg,
    unsigned long long* __restrict__ GA, unsigned long long* __restrict__ GB,
    unsigned* __restrict__ cnt, float4* __restrict__ ws_wet)
{
    __shared__ float4 fbL[4096];      // full 64x64 fb image (64 KB)
    __shared__ float fe[66];          // fade, zero pad at 0 and 65
    __shared__ float4 wvsL[36];       // [tap][cout] -> cin quad
    __shared__ float s_rw[16], s_dl[16];
    __shared__ float4 s_mlp[7];       // [0..1]=d1w rows, [2].xy=d1b, [3..6]=(d2w0,d2w1,d2b,fbb)

    const int tid = threadIdx.x;
    const int b   = blockIdx.x >> 3;
    const int blk = blockIdx.x & 7;

    if (tid < 66) {
        float f = 0.0f;
        if (tid >= 1 && tid <= 64) {
            int j = tid - 1;
            f = 1.0f;
            if (j < 4) f = 0.6f + (0.4f / 3.0f) * j;
            else if (j >= 60) f = 0.6f + (0.4f / 3.0f) * (63 - j);
        }
        fe[tid] = f;
    }
    if (tid >= 128 && tid < 164) {
        int t2 = tid - 128, n = t2 >> 2, co = t2 & 3;
        wvsL[t2] = make_float4(fbw[(co * 4 + 0) * 9 + n], fbw[(co * 4 + 1) * 9 + n],
                               fbw[(co * 4 + 2) * 9 + n], fbw[(co * 4 + 3) * 9 + n]);
    }
    if (tid >= 192 && tid < 208) s_rw[tid - 192] = rw[tid - 192];
    if (tid >= 256 && tid < 272) s_dl[tid - 256] = dl[tid - 256];
    if (tid == 320) {
        s_mlp[0] = make_float4(d1wg[0], d1wg[1], d1wg[2], d1wg[3]);
        s_mlp[1] = make_float4(d1wg[4], d1wg[5], d1wg[6], d1wg[7]);
        s_mlp[2] = make_float4(d1bg[0], d1bg[1], 0.0f, 0.0f);
        for (int c = 0; c < 4; ++c)
            s_mlp[3 + c] = make_float4(d2wg[c * 2], d2wg[c * 2 + 1], d2bg[c], fbb[c]);
    }
    // fb_0 = 0.1*x, full image (every block of this batch, redundantly)
    for (int s = tid; s < 4096; s += 512) {
        float4 v;
        v.x = 0.1f * x[((b * 4 + 0) << 12) + s];
        v.y = 0.1f * x[((b * 4 + 1) << 12) + s];
        v.z = 0.1f * x[((b * 4 + 2) << 12) + s];
        v.w = 0.1f * x[((b * 4 + 3) << 12) + s];
        fbL[s] = v;
    }
    __syncthreads();

    // LDS -> registers (re-reading LDS across barriers can't be CSE'd)
    float4 wr[9][4];
    #pragma unroll
    for (int n = 0; n < 9; ++n)
        #pragma unroll
        for (int co = 0; co < 4; ++co) wr[n][co] = wvsL[n * 4 + co];
    const float4 d1w0 = s_mlp[0], d1w1 = s_mlp[1];
    const float2 d1b = make_float2(s_mlp[2].x, s_mlp[2].y);
    float4 d2p[4] = { s_mlp[3], s_mlp[4], s_mlp[5], s_mlp[6] };

    const int ly = tid >> 6;              // 0..7
    const int y0 = (blk << 3) + ly;
    const int xx = tid & 63;
    float4 fbv = fbL[(y0 << 6) + xx];

    unsigned long long* Ab = GA + (b << 13);   // 4096 px * 2 ull per batch
    unsigned long long* Bb = GB + (b << 13);
    unsigned* cb = cnt + b * 240;              // 15 slots x 16 uints, 64B-spaced

    float acc0 = 0.0f, acc1 = 0.0f, acc2 = 0.0f, acc3 = 0.0f;
    float decay = 1.0f;
    #pragma unroll 1
    for (int i = 0; i < 16; ++i) {
        float d = s_dl[i];
        int ys  = ((int)(3.0f * d)) & 63;
        int xs  = ((int)(6.0f * d)) & 63;
        float wgt = fsig(s_rw[i]) * decay * 3.0f;

        float rv[4];
        conv_damp_l(fbL, y0, xx, ys, xs, fe, wr, d1w0, d1w1, d1b, d2p, rv);
        acc0 = fmaf(rv[0], wgt, acc0);
        acc1 = fmaf(rv[1], wgt, acc1);
        acc2 = fmaf(rv[2], wgt, acc2);
        acc3 = fmaf(rv[3], wgt, acc3);
        float4 g = make_float4(fbv.x + 0.24f * rv[0], fbv.y + 0.24f * rv[1],
                               fbv.z + 0.24f * rv[2], fbv.w + 0.24f * rv[3]);
        if (i == 15) break;

        unsigned long long* G = (i & 1) ? Bb : Ab;
        st_fb(G + (((y0 << 6) + xx) << 1), g);

        // per-batch barrier: syncthreads drains vmcnt(0) -> sc1 store visible
        __syncthreads();
        if (tid == 0) {
            if (__hip_atomic_fetch_add(&cb[i * 16], 1u, __ATOMIC_RELAXED,
                                       __HIP_MEMORY_SCOPE_AGENT) + 1u < 8u) {
                while (__hip_atomic_load(&cb[i * 16], __ATOMIC_RELAXED,
                                         __HIP_MEMORY_SCOPE_AGENT) < 8u)
                    __builtin_amdgcn_s_sleep(1);
            }
        }
        __syncthreads();

        int ys2 = ((int)(1.5f * d)) & 63;
        int xs2 = ((int)(3.0f * d)) & 63;
        float dn = s_dl[i + 1];
        int ysn = ((int)(3.0f * dn)) & 63;

        // own fbv for next iteration
        if (i > 0) {
            int yr = (y0 - ys2) & 63, xr = (xx - xs2) & 63;
            float4 g2 = ld_fb(G + (((yr << 6) + xr) << 1));
            float f = 0.08f * fe[y0 + 1] * fe[xx + 1];
            fbv = make_float4(fmaf(f, g2.x, g.x), fmaf(f, g2.y, g.y),
                              fmaf(f, g2.z, g.z), fmaf(f, g2.w, g.w));
        } else {
            fbv = g;
        }

        // reconstruct the 10 fb rows next iteration's conv will read:
        // rows r_j = (blk*8 - 1 + j - ysn) & 63, j = 0..9  (640 px)
        #pragma unroll
        for (int rpt = 0; rpt < 2; ++rpt) {
            int idx = tid + (rpt << 9);
            if (idx < 640) {
                int j  = idx >> 6, xc = idx & 63;
                int rr = ((blk << 3) - 1 + j - ysn) & 63;
                float4 g1 = ld_fb(G + (((rr << 6) + xc) << 1));
                float4 nv = g1;
                if (i > 0) {
                    int r2 = (rr - ys2) & 63, x2 = (xc - xs2) & 63;
                    float4 g2 = ld_fb(G + (((r2 << 6) + x2) << 1));
                    float f = 0.08f * fe[rr + 1] * fe[xc + 1];
                    nv = make_float4(fmaf(f, g2.x, g1.x), fmaf(f, g2.y, g1.y),
                                     fmaf(f, g2.z, g1.z), fmaf(f, g2.w, g1.w));
                }
                fbL[(rr << 6) + xc] = nv;
            }
        }
        __syncthreads();
        decay *= 0.8f;
    }

    ws_wet[(b << 12) + (y0 << 6) + xx] = make_float4(acc0, acc1, acc2, acc3);
}

// ---------------------------------------------------------------------------
// Kernel 2: attention (head_dim=1). Grid 512: b x h x 32 q-chunks of 128 rows.
// Exp-pipe split: rr 0,1 use trans-pipe v_exp_f32; rr 2,3 use VALU poly exp2
// (exp2_poly2). Whichever pipe was the issue bottleneck, load now splits
// ~50/50 across both. part[] aliases ksf (dead after inner loop).
// ---------------------------------------------------------------------------
__global__ __launch_bounds__(512) void attn_kernel(
    const float4* __restrict__ wet, const float* __restrict__ aiw,
    const float* __restrict__ aib, float* __restrict__ o_out)
{
    __shared__ float ksf[4096];          // keys (SoA); reused as part[] after barrier
    __shared__ float vsf[4096];          // values (SoA)
    __shared__ float redmx[8], redmn[8];

    const int tid = threadIdx.x;
    const int bid = blockIdx.x;
    const int b  = bid >> 7;
    const int h  = (bid >> 5) & 3;
    const int qc = bid & 31;

    float wq[4], wk[4], wv[4];
    #pragma unroll
    for (int c = 0; c < 4; ++c) {
        wq[c] = aiw[h * 4 + c];
        wk[c] = aiw[(4 + h) * 4 + c];
        wv[c] = aiw[(8 + h) * 4 + c];
    }
    const float bq = aib[h], bk = aib[4 + h], bv = aib[8 + h];

    float lmax = -1e30f, lmin = 1e30f;
    for (int s = tid; s < 4096; s += 512) {
        float4 w4 = wet[(b << 12) + s];
        float k = wk[0] * w4.x + wk[1] * w4.y + wk[2] * w4.z + wk[3] * w4.w + bk;
        float v = wv[0] * w4.x + wv[1] * w4.y + wv[2] * w4.z + wv[3] * w4.w + bv;
        ksf[s] = k; vsf[s] = v;
        lmax = fmaxf(lmax, k); lmin = fminf(lmin, k);
    }
    #pragma unroll
    for (int off = 32; off > 0; off >>= 1) {
        lmax = fmaxf(lmax, __shfl_xor(lmax, off));
        lmin = fminf(lmin, __shfl_xor(lmin, off));
    }
    if ((tid & 63) == 0) { redmx[tid >> 6] = lmax; redmn[tid >> 6] = lmin; }
    __syncthreads();
    float kmax = redmx[0], kmin = redmn[0];
    #pragma unroll
    for (int w = 1; w < 8; ++w) { kmax = fmaxf(kmax, redmx[w]); kmin = fminf(kmin, redmn[w]); }

    const int rs = tid & 31;
    const int kg = tid >> 5;
    v2f qL2[4], nmL2[4];
    #pragma unroll
    for (int rr = 0; rr < 4; ++rr) {
        int row = (qc << 7) + (rs << 2) + rr;
        float4 w4 = wet[(b << 12) + row];
        float q = wq[0] * w4.x + wq[1] * w4.y + wq[2] * w4.z + wq[3] * w4.w + bq;
        float m = (q >= 0.0f) ? q * kmax : q * kmin;   // exact row max (hd=1)
        float qL = q * LOG2E, mL = m * LOG2E;
        qL2[rr] = (v2f){qL, qL}; nmL2[rr] = (v2f){-mL, -mL};
    }

    const v2f* ks2 = (const v2f*)ksf;
    const v2f* vs2 = (const v2f*)vsf;
    v2f den2[4], num2[4];
    #pragma unroll
    for (int rr = 0; rr < 4; ++rr) { den2[rr] = (v2f){0.f, 0.f}; num2[rr] = (v2f){0.f, 0.f}; }

    const int j0 = kg << 6;
    #pragma unroll 4
    for (int j = j0 * 2; j < j0 * 2 + 128; ++j) {   // 128 v2f pairs = 256 keys
        v2f kk = ks2[j];
        v2f vv = vs2[j];
        #pragma unroll
        for (int rr = 0; rr < 4; ++rr) {
            v2f arg = __builtin_elementwise_fma(qL2[rr], kk, nmL2[rr]);
            v2f e;
            if (rr < 2) {                  // trans pipe
                e.x = __builtin_amdgcn_exp2f(arg.x);
                e.y = __builtin_amdgcn_exp2f(arg.y);
            } else {                       // VALU pipe
                e = exp2_poly2(arg);
            }
            den2[rr] += e;
            num2[rr] = __builtin_elementwise_fma(e, vv, num2[rr]);
        }
    }
    __syncthreads();                      // all waves done reading ksf -> alias as part
    float2* part = (float2*)ksf;          // [kg][row_local], 2048 float2 = 16 KB
    #pragma unroll
    for (int rr = 0; rr < 4; ++rr)
        part[(kg << 7) + (rs << 2) + rr] =
            make_float2(den2[rr].x + den2[rr].y, num2[rr].x + num2[rr].y);
    __syncthreads();
    if (tid < 128) {
        float dd = 0.0f, nn = 0.0f;
        #pragma unroll
        for (int g = 0; g < 16; ++g) {
            float2 p = part[(g << 7) + tid];
            dd += p.x; nn += p.y;
        }
        int row = (qc << 7) + tid;
        o_out[((b << 12) + row) * 4 + h] = nn * __builtin_amdgcn_rcpf(dd);
    }
}

// ---------------------------------------------------------------------------
// Kernel 3 (fused tail): attn out-projection + box blur + edge enhance +
// spatial conv + 1x1 combine + dry/wet mix. 64 blocks: b x 16 bands of 4 rows.
// ---------------------------------------------------------------------------
__global__ __launch_bounds__(256) void tail_kernel(
    const float4* __restrict__ o_in, const float* __restrict__ aow,
    const float* __restrict__ aob, const float* __restrict__ x,
    const float* __restrict__ sw, const float* __restrict__ sb,
    const float* __restrict__ ow, const float* __restrict__ ob,
    float* __restrict__ out)
{
    __shared__ float wetp[4][8][64];    // proj(o) rows y0-2..y0+5
    __shared__ float blurL[4][6][64];   // blur rows y0-1..y0+4
    __shared__ float xL[4][6][64];      // x rows y0-1..y0+4
    __shared__ float s_sw[288], s_ow[48], s_sb[8], s_ob[4];

    const int tid  = threadIdx.x;
    const int b    = blockIdx.x >> 4;
    const int band = blockIdx.x & 15;
    const int y0   = band << 2;

    float pw[4][4], pb[4];
    #pragma unroll
    for (int c = 0; c < 4; ++c) {
        #pragma unroll
        for (int h = 0; h < 4; ++h) pw[c][h] = aow[c * 4 + h];
        pb[c] = aob[c];
    }

    for (int j = tid; j < 288; j += 256) s_sw[j] = sw[j];
    if (tid < 48) s_ow[tid] = ow[tid];
    if (tid < 8)  s_sb[tid] = sb[tid];
    if (tid < 4)  s_ob[tid] = ob[tid];

    for (int s = tid; s < 512; s += 256) {
        int lr = s >> 6, xx = s & 63;
        int gy = y0 - 2 + lr;
        float4 o = make_float4(0.f, 0.f, 0.f, 0.f);
        if (gy >= 0 && gy < 64) o = o_in[(b << 12) + (gy << 6) + xx];
        #pragma unroll
        for (int c = 0; c < 4; ++c)
            wetp[c][lr][xx] = (gy >= 0 && gy < 64)
                ? pw[c][0]*o.x + pw[c][1]*o.y + pw[c][2]*o.z + pw[c][3]*o.w + pb[c]
                : 0.0f;
    }
    for (int s = tid; s < 1536; s += 256) {
        int c = s / 384, rm = s - c * 384;
        int r = rm >> 6, xx = rm & 63;
        int gy = y0 - 1 + r;
        float v = 0.f;
        if (gy >= 0 && gy < 64) v = x[((b * 4 + c) << 12) + (gy << 6) + xx];
        xL[c][r][xx] = v;
    }
    __syncthreads();

    for (int s = tid; s < 1536; s += 256) {
        int c = s / 384, rm = s - c * 384;
        int r = rm >> 6, xx = rm & 63;
        int gy = y0 - 1 + r;
        float acc = 0.f;
        if (gy >= 0 && gy < 64) {
            #pragma unroll
            for (int dy = 0; dy < 3; ++dy) {
                #pragma unroll
                for (int dx = -1; dx <= 1; ++dx) {
                    int xc = xx + dx;
                    if (xc >= 0 && xc <= 63) acc += wetp[c][r + dy][xc];
                }
            }
        }
        blurL[c][r][xx] = acc * (1.0f / 9.0f);
    }
    __syncthreads();

    {
        const int lyq = tid >> 6, xx = tid & 63;
        const int gy = y0 + lyq;

        float spat[8];
        #pragma unroll
        for (int co = 0; co < 8; ++co) spat[co] = s_sb[co];
        #pragma unroll
        for (int dy = 0; dy < 3; ++dy) {
            #pragma unroll
            for (int dx = -1; dx <= 1; ++dx) {
                int xc = xx + dx;
                if (xc < 0 || xc > 63) continue;
                int kx = dx + 1;
                #pragma unroll
                for (int ci = 0; ci < 4; ++ci) {
                    float xv = xL[ci][lyq + dy][xc];
                    #pragma unroll
                    for (int co = 0; co < 8; ++co)
                        spat[co] += s_sw[((co * 4 + ci) * 3 + dy) * 3 + kx] * xv;
                }
            }
        }

        float wetF[4];
        #pragma unroll
        for (int c = 0; c < 4; ++c) {
            float center = blurL[c][lyq + 1][xx];
            float sum9 = 0.f;
            #pragma unroll
            for (int dy = 0; dy < 3; ++dy) {
                #pragma unroll
                for (int dx = -1; dx <= 1; ++dx) {
                    int xc = xx + dx;
                    if (xc >= 0 && xc <= 63) sum9 += blurL[c][lyq + dy][xc];
                }
            }
            wetF[c] = center + 0.04f * (9.0f * center - sum9);
        }

        #pragma unroll
        for (int co = 0; co < 4; ++co) {
            float p = s_ob[co];
            #pragma unroll
            for (int j = 0; j < 8; ++j) p += s_ow[co * 12 + j] * spat[j];
            #pragma unroll
            for (int c = 0; c < 4; ++c) p += s_ow[co * 12 + 8 + c] * wetF[c];
            float xc = xL[co][lyq + 1][xx];
            out[((b * 4 + co) << 12) + (gy << 6) + xx] = 0.7f * xc + 0.3f * p;
        }
    }
}

// ---------------------------------------------------------------------------
extern "C" void kernel_launch(void* const* d_in, const int* in_sizes, int n_in,
                              void* d_out, int out_size, void* d_ws, size_t ws_size,
                              hipStream_t stream)
{
    (void)in_sizes; (void)n_in; (void)out_size; (void)ws_size;
    const float* x    = (const float*)d_in[0];
    const float* rw   = (const float*)d_in[1];
    const float* dl   = (const float*)d_in[2];
    // d_in[3] diffusion_strength: unused by reference
    const float* sw   = (const float*)d_in[4];
    const float* sb   = (const float*)d_in[5];
    const float* fbw  = (const float*)d_in[6];
    const float* fbb  = (const float*)d_in[7];
    const float* d1w  = (const float*)d_in[8];
    const float* d1b  = (const float*)d_in[9];
    const float* d2w  = (const float*)d_in[10];
    const float* d2b  = (const float*)d_in[11];
    const float* aiw  = (const float*)d_in[12];
    const float* aib  = (const float*)d_in[13];
    const float* aow  = (const float*)d_in[14];
    const float* aob  = (const float*)d_in[15];
    const float* ow   = (const float*)d_in[16];
    const float* ob   = (const float*)d_in[17];
    float* out = (float*)d_out;

    // ws layout (768 KB proven):
    float* ws_wet  = (float*)d_ws;                   // [4][4096] float4  (256 KB)
    float* GA      = ws_wet + 65536;                 // [4][4096] float4  (256 KB); reused as ws_o
    float* GB      = GA + 65536;                     // [4][4096] float4  (256 KB)
    unsigned* cnt  = (unsigned*)(GB + 65536);        // 4 KB counters (4 batches x 15 slots)
    float* ws_o    = GA;

    bar_init<<<1, 256, 0, stream>>>(cnt);
    reverb_mb<<<RNB, 512, 0, stream>>>(x, rw, dl, fbw, fbb, d1w, d1b, d2w, d2b,
                                       (unsigned long long*)GA, (unsigned long long*)GB,
                                       cnt, (float4*)ws_wet);
    attn_kernel<<<512, 512, 0, stream>>>((const float4*)ws_wet, aiw, aib, ws_o);
    tail_kernel<<<64, 256, 0, stream>>>((const float4*)ws_o, aow, aob, x,
                                        sw, sb, ow, ob, out);
}

// Round 11
// 180.456 us; speedup vs baseline: 1.1193x; 1.1193x over previous
//
#include <hip/hip_runtime.h>

#define LOG2E 1.4426950408889634f
#define RNB 32   // reverb grid blocks: 4 batches x 8 blocks; per-batch counted barrier

typedef float v2f __attribute__((ext_vector_type(2)));

// fast sigmoid: rcp approx ~1e-6 rel; tolerance headroom is ~250x
__device__ __forceinline__ float fsig(float z) {
    return __builtin_amdgcn_rcpf(1.0f + exp2f(-z * LOG2E));
}

// ---------------------------------------------------------------------------
// Device-coherent g-buffer access: relaxed agent-scope atomics -> sc1
// load/store (bypass non-coherent L1/L2, served at the device coherence
// point). Per-access coherence => no wbl2/inv fences anywhere.
// ---------------------------------------------------------------------------
__device__ __forceinline__ float4 ld_fb(const unsigned long long* p) {
    unsigned long long a = __hip_atomic_load(p,     __ATOMIC_RELAXED, __HIP_MEMORY_SCOPE_AGENT);
    unsigned long long b = __hip_atomic_load(p + 1, __ATOMIC_RELAXED, __HIP_MEMORY_SCOPE_AGENT);
    float2 lo = __builtin_bit_cast(float2, a);
    float2 hi = __builtin_bit_cast(float2, b);
    return make_float4(lo.x, lo.y, hi.x, hi.y);
}

__device__ __forceinline__ void st_fb(unsigned long long* p, float4 v) {
    __hip_atomic_store(p,     __builtin_bit_cast(unsigned long long, make_float2(v.x, v.y)),
                       __ATOMIC_RELAXED, __HIP_MEMORY_SCOPE_AGENT);
    __hip_atomic_store(p + 1, __builtin_bit_cast(unsigned long long, make_float2(v.z, v.w)),
                       __ATOMIC_RELAXED, __HIP_MEMORY_SCOPE_AGENT);
}

__global__ __launch_bounds__(256) void bar_init(unsigned* cnt) {
    for (int j = threadIdx.x; j < 1024; j += 256) cnt[j] = 0u;   // 4 batches x 15 slots x 64B
}

// ---------------------------------------------------------------------------
// conv3x3(roll(fb)*fade) + damping MLP at one pixel, fb in LDS (full image
// replicated per block). Weights live in VGPRs (wr), fades in LDS.
// ---------------------------------------------------------------------------
__device__ __forceinline__ void conv_damp_l(
    const float4* __restrict__ src, int yq, int xq, int ys, int xs,
    const float* fe, const float4 wr[9][4],
    const float4 d1w0, const float4 d1w1, const float2 d1b, const float4 d2p[4],
    float rv[4])
{
    float r[4] = { d2p[0].w, d2p[1].w, d2p[2].w, d2p[3].w };   // conv bias (fbb)
    #pragma unroll
    for (int a = 0; a < 3; ++a) {
        int yy = yq - 1 + a;
        float fy = fe[yy + 1];                       // 0 outside image -> zero pad
        const float4* rowp = src + (((yy - ys) & 63) << 6);
        #pragma unroll
        for (int qq = 0; qq < 3; ++qq) {
            int xt = xq - 1 + qq;
            float f = fy * fe[xt + 1];
            float4 v = rowp[(xt - xs) & 63];
            float s0 = v.x * f, s1 = v.y * f, s2 = v.z * f, s3 = v.w * f;
            #pragma unroll
            for (int co = 0; co < 4; ++co) {
                float4 w = wr[a * 3 + qq][co];
                r[co] = fmaf(w.x, s0, fmaf(w.y, s1, fmaf(w.z, s2, fmaf(w.w, s3, r[co]))));
            }
        }
    }
    float z0 = fmaf(d1w0.x, r[0], fmaf(d1w0.y, r[1], fmaf(d1w0.z, r[2], fmaf(d1w0.w, r[3], d1b.x))));
    float z1 = fmaf(d1w1.x, r[0], fmaf(d1w1.y, r[1], fmaf(d1w1.z, r[2], fmaf(d1w1.w, r[3], d1b.y))));
    float h0 = z0 * fsig(z0);
    float h1 = z1 * fsig(z1);
    #pragma unroll
    for (int c = 0; c < 4; ++c) {
        float dm = fsig(fmaf(d2p[c].x, h0, fmaf(d2p[c].y, h1, d2p[c].z)));
        rv[c] = r[c] * dm;
    }
}

// ---------------------------------------------------------------------------
// Kernel 1: multi-block reverb, LDS-replicated state. R3-EXACT (measured
// 48.8us): counted per-batch barrier, tid0 sole adder+poller, block-wide
// release via second syncthreads. R4/R5/R7/R8 lessons: more pollers, fewer
// barriers, and single-CU variants all regress.
// ---------------------------------------------------------------------------
__global__ __launch_bounds__(512) void reverb_mb(
    const float* __restrict__ x, const float* __restrict__ rw, const float* __restrict__ dl,
    const float* __restrict__ fbw, const float* __restrict__ fbb,
    const float* __restrict__ d1wg, const float* __restrict__ d1bg,
    const float* __restrict__ d2wg, const float* __restrict__ d2bg,
    unsigned long long* __restrict__ GA, unsigned long long* __restrict__ GB,
    unsigned* __restrict__ cnt, float4* __restrict__ ws_wet)
{
    __shared__ float4 fbL[4096];      // full 64x64 fb image (64 KB)
    __shared__ float fe[66];          // fade, zero pad at 0 and 65
    __shared__ float4 wvsL[36];       // [tap][cout] -> cin quad
    __shared__ float s_rw[16], s_dl[16];
    __shared__ float4 s_mlp[7];       // [0..1]=d1w rows, [2].xy=d1b, [3..6]=(d2w0,d2w1,d2b,fbb)

    const int tid = threadIdx.x;
    const int b   = blockIdx.x >> 3;
    const int blk = blockIdx.x & 7;

    if (tid < 66) {
        float f = 0.0f;
        if (tid >= 1 && tid <= 64) {
            int j = tid - 1;
            f = 1.0f;
            if (j < 4) f = 0.6f + (0.4f / 3.0f) * j;
            else if (j >= 60) f = 0.6f + (0.4f / 3.0f) * (63 - j);
        }
        fe[tid] = f;
    }
    if (tid >= 128 && tid < 164) {
        int t2 = tid - 128, n = t2 >> 2, co = t2 & 3;
        wvsL[t2] = make_float4(fbw[(co * 4 + 0) * 9 + n], fbw[(co * 4 + 1) * 9 + n],
                               fbw[(co * 4 + 2) * 9 + n], fbw[(co * 4 + 3) * 9 + n]);
    }
    if (tid >= 192 && tid < 208) s_rw[tid - 192] = rw[tid - 192];
    if (tid >= 256 && tid < 272) s_dl[tid - 256] = dl[tid - 256];
    if (tid == 320) {
        s_mlp[0] = make_float4(d1wg[0], d1wg[1], d1wg[2], d1wg[3]);
        s_mlp[1] = make_float4(d1wg[4], d1wg[5], d1wg[6], d1wg[7]);
        s_mlp[2] = make_float4(d1bg[0], d1bg[1], 0.0f, 0.0f);
        for (int c = 0; c < 4; ++c)
            s_mlp[3 + c] = make_float4(d2wg[c * 2], d2wg[c * 2 + 1], d2bg[c], fbb[c]);
    }
    // fb_0 = 0.1*x, full image (every block of this batch, redundantly)
    for (int s = tid; s < 4096; s += 512) {
        float4 v;
        v.x = 0.1f * x[((b * 4 + 0) << 12) + s];
        v.y = 0.1f * x[((b * 4 + 1) << 12) + s];
        v.z = 0.1f * x[((b * 4 + 2) << 12) + s];
        v.w = 0.1f * x[((b * 4 + 3) << 12) + s];
        fbL[s] = v;
    }
    __syncthreads();

    // LDS -> registers (re-reading LDS across barriers can't be CSE'd)
    float4 wr[9][4];
    #pragma unroll
    for (int n = 0; n < 9; ++n)
        #pragma unroll
        for (int co = 0; co < 4; ++co) wr[n][co] = wvsL[n * 4 + co];
    const float4 d1w0 = s_mlp[0], d1w1 = s_mlp[1];
    const float2 d1b = make_float2(s_mlp[2].x, s_mlp[2].y);
    float4 d2p[4] = { s_mlp[3], s_mlp[4], s_mlp[5], s_mlp[6] };

    const int ly = tid >> 6;              // 0..7
    const int y0 = (blk << 3) + ly;
    const int xx = tid & 63;
    float4 fbv = fbL[(y0 << 6) + xx];

    unsigned long long* Ab = GA + (b << 13);   // 4096 px * 2 ull per batch
    unsigned long long* Bb = GB + (b << 13);
    unsigned* cb = cnt + b * 240;              // 15 slots x 16 uints, 64B-spaced

    float acc0 = 0.0f, acc1 = 0.0f, acc2 = 0.0f, acc3 = 0.0f;
    float decay = 1.0f;
    #pragma unroll 1
    for (int i = 0; i < 16; ++i) {
        float d = s_dl[i];
        int ys  = ((int)(3.0f * d)) & 63;
        int xs  = ((int)(6.0f * d)) & 63;
        float wgt = fsig(s_rw[i]) * decay * 3.0f;

        float rv[4];
        conv_damp_l(fbL, y0, xx, ys, xs, fe, wr, d1w0, d1w1, d1b, d2p, rv);
        acc0 = fmaf(rv[0], wgt, acc0);
        acc1 = fmaf(rv[1], wgt, acc1);
        acc2 = fmaf(rv[2], wgt, acc2);
        acc3 = fmaf(rv[3], wgt, acc3);
        float4 g = make_float4(fbv.x + 0.24f * rv[0], fbv.y + 0.24f * rv[1],
                               fbv.z + 0.24f * rv[2], fbv.w + 0.24f * rv[3]);
        if (i == 15) break;

        unsigned long long* G = (i & 1) ? Bb : Ab;
        st_fb(G + (((y0 << 6) + xx) << 1), g);

        // per-batch barrier: syncthreads drains vmcnt(0) -> sc1 store visible
        __syncthreads();
        if (tid == 0) {
            if (__hip_atomic_fetch_add(&cb[i * 16], 1u, __ATOMIC_RELAXED,
                                       __HIP_MEMORY_SCOPE_AGENT) + 1u < 8u) {
                while (__hip_atomic_load(&cb[i * 16], __ATOMIC_RELAXED,
                                         __HIP_MEMORY_SCOPE_AGENT) < 8u)
                    __builtin_amdgcn_s_sleep(1);
            }
        }
        __syncthreads();

        int ys2 = ((int)(1.5f * d)) & 63;
        int xs2 = ((int)(3.0f * d)) & 63;
        float dn = s_dl[i + 1];
        int ysn = ((int)(3.0f * dn)) & 63;

        // own fbv for next iteration
        if (i > 0) {
            int yr = (y0 - ys2) & 63, xr = (xx - xs2) & 63;
            float4 g2 = ld_fb(G + (((yr << 6) + xr) << 1));
            float f = 0.08f * fe[y0 + 1] * fe[xx + 1];
            fbv = make_float4(fmaf(f, g2.x, g.x), fmaf(f, g2.y, g.y),
                              fmaf(f, g2.z, g.z), fmaf(f, g2.w, g.w));
        } else {
            fbv = g;
        }

        // reconstruct the 10 fb rows next iteration's conv will read:
        // rows r_j = (blk*8 - 1 + j - ysn) & 63, j = 0..9  (640 px)
        #pragma unroll
        for (int rpt = 0; rpt < 2; ++rpt) {
            int idx = tid + (rpt << 9);
            if (idx < 640) {
                int j  = idx >> 6, xc = idx & 63;
                int rr = ((blk << 3) - 1 + j - ysn) & 63;
                float4 g1 = ld_fb(G + (((rr << 6) + xc) << 1));
                float4 nv = g1;
                if (i > 0) {
                    int r2 = (rr - ys2) & 63, x2 = (xc - xs2) & 63;
                    float4 g2 = ld_fb(G + (((r2 << 6) + x2) << 1));
                    float f = 0.08f * fe[rr + 1] * fe[xc + 1];
                    nv = make_float4(fmaf(f, g2.x, g1.x), fmaf(f, g2.y, g1.y),
                                     fmaf(f, g2.z, g1.z), fmaf(f, g2.w, g1.w));
                }
                fbL[(rr << 6) + xc] = nv;
            }
        }
        __syncthreads();
        decay *= 0.8f;
    }

    ws_wet[(b << 12) + (y0 << 6) + xx] = make_float4(acc0, acc1, acc2, acc3);
}

// ---------------------------------------------------------------------------
// Kernel 2: attention (head_dim=1). Grid 1024: b x h x 64 q-chunks of 64 rows
// (R10 lesson: exp is VALU-class, attn is exp-LATENCY-bound at 2 blocks/CU;
// poly-offload to VALU strictly worse). 512 threads = 16 row-slots (4 rows)
// x 32 key-groups; LDS 32.2 KB -> 4 blocks/CU co-resident = 32 waves/CU for
// trans-latency hiding. Key-groups take INTERLEAVED v2f indices (j=jj*32+kg)
// so the 4 kg-groups within a wave hit consecutive banks (contiguous chunks
// would alias 4-way on the same bank pair). Pure v_exp_f32 restored.
// ---------------------------------------------------------------------------
__global__ __launch_bounds__(512) void attn_kernel(
    const float4* __restrict__ wet, const float* __restrict__ aiw,
    const float* __restrict__ aib, float* __restrict__ o_out)
{
    __shared__ float ksf[4096];          // keys (SoA); reused as part[] after barrier
    __shared__ float vsf[4096];          // values (SoA)
    __shared__ float redmx[8], redmn[8];

    const int tid = threadIdx.x;
    const int bid = blockIdx.x;
    const int b  = bid >> 8;
    const int h  = (bid >> 6) & 3;
    const int qc = bid & 63;             // 64 chunks of 64 rows

    float wq[4], wk[4], wv[4];
    #pragma unroll
    for (int c = 0; c < 4; ++c) {
        wq[c] = aiw[h * 4 + c];
        wk[c] = aiw[(4 + h) * 4 + c];
        wv[c] = aiw[(8 + h) * 4 + c];
    }
    const float bq = aib[h], bk = aib[4 + h], bv = aib[8 + h];

    float lmax = -1e30f, lmin = 1e30f;
    for (int s = tid; s < 4096; s += 512) {
        float4 w4 = wet[(b << 12) + s];
        float k = wk[0] * w4.x + wk[1] * w4.y + wk[2] * w4.z + wk[3] * w4.w + bk;
        float v = wv[0] * w4.x + wv[1] * w4.y + wv[2] * w4.z + wv[3] * w4.w + bv;
        ksf[s] = k; vsf[s] = v;
        lmax = fmaxf(lmax, k); lmin = fminf(lmin, k);
    }
    #pragma unroll
    for (int off = 32; off > 0; off >>= 1) {
        lmax = fmaxf(lmax, __shfl_xor(lmax, off));
        lmin = fminf(lmin, __shfl_xor(lmin, off));
    }
    if ((tid & 63) == 0) { redmx[tid >> 6] = lmax; redmn[tid >> 6] = lmin; }
    __syncthreads();
    float kmax = redmx[0], kmin = redmn[0];
    #pragma unroll
    for (int w = 1; w < 8; ++w) { kmax = fmaxf(kmax, redmx[w]); kmin = fminf(kmin, redmn[w]); }

    const int rs = tid & 15;             // 16 row slots x 4 rows = 64 rows
    const int kg = tid >> 4;             // 32 key groups x 128 keys
    v2f qL2[4], nmL2[4];
    #pragma unroll
    for (int rr = 0; rr < 4; ++rr) {
        int row = (qc << 6) + (rs << 2) + rr;
        float4 w4 = wet[(b << 12) + row];
        float q = wq[0] * w4.x + wq[1] * w4.y + wq[2] * w4.z + wq[3] * w4.w + bq;
        float m = (q >= 0.0f) ? q * kmax : q * kmin;   // exact row max (hd=1)
        float qL = q * LOG2E, mL = m * LOG2E;
        qL2[rr] = (v2f){qL, qL}; nmL2[rr] = (v2f){-mL, -mL};
    }

    const v2f* ks2 = (const v2f*)ksf;
    const v2f* vs2 = (const v2f*)vsf;
    v2f den2[4], num2[4];
    #pragma unroll
    for (int rr = 0; rr < 4; ++rr) { den2[rr] = (v2f){0.f, 0.f}; num2[rr] = (v2f){0.f, 0.f}; }

    #pragma unroll 4
    for (int jj = 0; jj < 64; ++jj) {    // 64 v2f pairs = 128 keys per group
        int j = (jj << 5) + kg;          // interleaved: consecutive banks across kg
        v2f kk = ks2[j];
        v2f vv = vs2[j];
        #pragma unroll
        for (int rr = 0; rr < 4; ++rr) {
            v2f arg = __builtin_elementwise_fma(qL2[rr], kk, nmL2[rr]);
            v2f e;
            e.x = __builtin_amdgcn_exp2f(arg.x);
            e.y = __builtin_amdgcn_exp2f(arg.y);
            den2[rr] += e;
            num2[rr] = __builtin_elementwise_fma(e, vv, num2[rr]);
        }
    }
    __syncthreads();                      // all waves done reading ksf -> alias as part
    float2* part = (float2*)ksf;          // [kg 32][row_local 64] = 2048 float2 = 16 KB
    #pragma unroll
    for (int rr = 0; rr < 4; ++rr)
        part[(kg << 6) + (rs << 2) + rr] =
            make_float2(den2[rr].x + den2[rr].y, num2[rr].x + num2[rr].y);
    __syncthreads();
    if (tid < 64) {
        float dd = 0.0f, nn = 0.0f;
        #pragma unroll
        for (int g = 0; g < 32; ++g) {
            float2 p = part[(g << 6) + tid];
            dd += p.x; nn += p.y;
        }
        int row = (qc << 6) + tid;
        o_out[((b << 12) + row) * 4 + h] = nn * __builtin_amdgcn_rcpf(dd);
    }
}

// ---------------------------------------------------------------------------
// Kernel 3 (fused tail): attn out-projection + box blur + edge enhance +
// spatial conv + 1x1 combine + dry/wet mix. 64 blocks: b x 16 bands of 4 rows.
// ---------------------------------------------------------------------------
__global__ __launch_bounds__(256) void tail_kernel(
    const float4* __restrict__ o_in, const float* __restrict__ aow,
    const float* __restrict__ aob, const float* __restrict__ x,
    const float* __restrict__ sw, const float* __restrict__ sb,
    const float* __restrict__ ow, const float* __restrict__ ob,
    float* __restrict__ out)
{
    __shared__ float wetp[4][8][64];    // proj(o) rows y0-2..y0+5
    __shared__ float blurL[4][6][64];   // blur rows y0-1..y0+4
    __shared__ float xL[4][6][64];      // x rows y0-1..y0+4
    __shared__ float s_sw[288], s_ow[48], s_sb[8], s_ob[4];

    const int tid  = threadIdx.x;
    const int b    = blockIdx.x >> 4;
    const int band = blockIdx.x & 15;
    const int y0   = band << 2;

    float pw[4][4], pb[4];
    #pragma unroll
    for (int c = 0; c < 4; ++c) {
        #pragma unroll
        for (int h = 0; h < 4; ++h) pw[c][h] = aow[c * 4 + h];
        pb[c] = aob[c];
    }

    for (int j = tid; j < 288; j += 256) s_sw[j] = sw[j];
    if (tid < 48) s_ow[tid] = ow[tid];
    if (tid < 8)  s_sb[tid] = sb[tid];
    if (tid < 4)  s_ob[tid] = ob[tid];

    for (int s = tid; s < 512; s += 256) {
        int lr = s >> 6, xx = s & 63;
        int gy = y0 - 2 + lr;
        float4 o = make_float4(0.f, 0.f, 0.f, 0.f);
        if (gy >= 0 && gy < 64) o = o_in[(b << 12) + (gy << 6) + xx];
        #pragma unroll
        for (int c = 0; c < 4; ++c)
            wetp[c][lr][xx] = (gy >= 0 && gy < 64)
                ? pw[c][0]*o.x + pw[c][1]*o.y + pw[c][2]*o.z + pw[c][3]*o.w + pb[c]
                : 0.0f;
    }
    for (int s = tid; s < 1536; s += 256) {
        int c = s / 384, rm = s - c * 384;
        int r = rm >> 6, xx = rm & 63;
        int gy = y0 - 1 + r;
        float v = 0.f;
        if (gy >= 0 && gy < 64) v = x[((b * 4 + c) << 12) + (gy << 6) + xx];
        xL[c][r][xx] = v;
    }
    __syncthreads();

    for (int s = tid; s < 1536; s += 256) {
        int c = s / 384, rm = s - c * 384;
        int r = rm >> 6, xx = rm & 63;
        int gy = y0 - 1 + r;
        float acc = 0.f;
        if (gy >= 0 && gy < 64) {
            #pragma unroll
            for (int dy = 0; dy < 3; ++dy) {
                #pragma unroll
                for (int dx = -1; dx <= 1; ++dx) {
                    int xc = xx + dx;
                    if (xc >= 0 && xc <= 63) acc += wetp[c][r + dy][xc];
                }
            }
        }
        blurL[c][r][xx] = acc * (1.0f / 9.0f);
    }
    __syncthreads();

    {
        const int lyq = tid >> 6, xx = tid & 63;
        const int gy = y0 + lyq;

        float spat[8];
        #pragma unroll
        for (int co = 0; co < 8; ++co) spat[co] = s_sb[co];
        #pragma unroll
        for (int dy = 0; dy < 3; ++dy) {
            #pragma unroll
            for (int dx = -1; dx <= 1; ++dx) {
                int xc = xx + dx;
                if (xc < 0 || xc > 63) continue;
                int kx = dx + 1;
                #pragma unroll
                for (int ci = 0; ci < 4; ++ci) {
                    float xv = xL[ci][lyq + dy][xc];
                    #pragma unroll
                    for (int co = 0; co < 8; ++co)
                        spat[co] += s_sw[((co * 4 + ci) * 3 + dy) * 3 + kx] * xv;
                }
            }
        }

        float wetF[4];
        #pragma unroll
        for (int c = 0; c < 4; ++c) {
            float center = blurL[c][lyq + 1][xx];
            float sum9 = 0.f;
            #pragma unroll
            for (int dy = 0; dy < 3; ++dy) {
                #pragma unroll
                for (int dx = -1; dx <= 1; ++dx) {
                    int xc = xx + dx;
                    if (xc >= 0 && xc <= 63) sum9 += blurL[c][lyq + dy][xc];
                }
            }
            wetF[c] = center + 0.04f * (9.0f * center - sum9);
        }

        #pragma unroll
        for (int co = 0; co < 4; ++co) {
            float p = s_ob[co];
            #pragma unroll
            for (int j = 0; j < 8; ++j) p += s_ow[co * 12 + j] * spat[j];
            #pragma unroll
            for (int c = 0; c < 4; ++c) p += s_ow[co * 12 + 8 + c] * wetF[c];
            float xc = xL[co][lyq + 1][xx];
            out[((b * 4 + co) << 12) + (gy << 6) + xx] = 0.7f * xc + 0.3f * p;
        }
    }
}

// ---------------------------------------------------------------------------
extern "C" void kernel_launch(void* const* d_in, const int* in_sizes, int n_in,
                              void* d_out, int out_size, void* d_ws, size_t ws_size,
                              hipStream_t stream)
{
    (void)in_sizes; (void)n_in; (void)out_size; (void)ws_size;
    const float* x    = (const float*)d_in[0];
    const float* rw   = (const float*)d_in[1];
    const float* dl   = (const float*)d_in[2];
    // d_in[3] diffusion_strength: unused by reference
    const float* sw   = (const float*)d_in[4];
    const float* sb   = (const float*)d_in[5];
    const float* fbw  = (const float*)d_in[6];
    const float* fbb  = (const float*)d_in[7];
    const float* d1w  = (const float*)d_in[8];
    const float* d1b  = (const float*)d_in[9];
    const float* d2w  = (const float*)d_in[10];
    const float* d2b  = (const float*)d_in[11];
    const float* aiw  = (const float*)d_in[12];
    const float* aib  = (const float*)d_in[13];
    const float* aow  = (const float*)d_in[14];
    const float* aob  = (const float*)d_in[15];
    const float* ow   = (const float*)d_in[16];
    const float* ob   = (const float*)d_in[17];
    float* out = (float*)d_out;

    // ws layout (768 KB proven):
    float* ws_wet  = (float*)d_ws;                   // [4][4096] float4  (256 KB)
    float* GA      = ws_wet + 65536;                 // [4][4096] float4  (256 KB); reused as ws_o
    float* GB      = GA + 65536;                     // [4][4096] float4  (256 KB)
    unsigned* cnt  = (unsigned*)(GB + 65536);        // 4 KB counters (4 batches x 15 slots)
    float* ws_o    = GA;

    bar_init<<<1, 256, 0, stream>>>(cnt);
    reverb_mb<<<RNB, 512, 0, stream>>>(x, rw, dl, fbw, fbb, d1w, d1b, d2w, d2b,
                                       (unsigned long long*)GA, (unsigned long long*)GB,
                                       cnt, (float4*)ws_wet);
    attn_kernel<<<1024, 512, 0, stream>>>((const float4*)ws_wet, aiw, aib, ws_o);
    tail_kernel<<<64, 256, 0, stream>>>((const float4*)ws_o, aow, aob, x,
                                        sw, sb, ow, ob, out);
}